// Round 1
// 594.064 us; speedup vs baseline: 1.0335x; 1.0335x over previous
//
#include <hip/hip_runtime.h>
#include <cstdint>
#include <cstddef>

#define MM 65536
#define NN 1024
#define KK 1024
#define NT 16  // KK / 64 K-tiles

typedef __bf16 bf16x8 __attribute__((ext_vector_type(8)));
typedef float f32x4 __attribute__((ext_vector_type(4)));

typedef const __attribute__((address_space(1))) unsigned int* gas_t;
typedef __attribute__((address_space(3))) unsigned int* las_t;

__device__ __forceinline__ void gll16(const void* g, void* l) {
  __builtin_amdgcn_global_load_lds((gas_t)g, (las_t)l, 16, 0, 0);
}

// exp2 for integer e in [-126, 127]
__device__ __forceinline__ float exp2i(int e) {
  return __int_as_float((e + 127) << 23);
}

__device__ __forceinline__ f32x4 mfma(bf16x8 a, bf16x8 b, f32x4 c) {
  return __builtin_amdgcn_mfma_f32_16x16x32_bf16(a, b, c, 0, 0, 0);
}

// MXFP fake-quant (block=32 along last dim), fp32 -> exact bf16.
// One float4 per lane; 8 consecutive lanes = one 32-elem block. (unchanged)
__global__ __launch_bounds__(256) void mxfp_quant(const float* __restrict__ in,
                                                  unsigned short* __restrict__ out) {
  size_t i = (size_t)blockIdx.x * 256 + threadIdx.x;
  float4 v = ((const float4*)in)[i];
  float a = fmaxf(fmaxf(fabsf(v.x), fabsf(v.y)), fmaxf(fabsf(v.z), fabsf(v.w)));
  a = fmaxf(a, __shfl_xor(a, 1));
  a = fmaxf(a, __shfl_xor(a, 2));
  a = fmaxf(a, __shfl_xor(a, 4));
  int ebits = (int)((__float_as_uint(a) >> 23) & 0xff);
  int se = (ebits > 0 ? ebits : 1) - 127 - 8;
  se = se < -126 ? -126 : se;
  float sinv = exp2i(-se);
  float sc = exp2i(se);

  float e[4] = {v.x, v.y, v.z, v.w};
  unsigned short o[4];
#pragma unroll
  for (int c = 0; c < 4; ++c) {
    float vv = e[c] * sinv;
    int pe = (int)((__float_as_uint(vv) >> 23) & 0xff) - 127;
    pe = pe < -6 ? -6 : pe;
    float r = floorf(fabsf(vv) * exp2i(6 - pe) + 0.5f);
    float q = copysignf(r * exp2i(pe - 6), vv);
    q = fminf(fmaxf(q, -448.f), 448.f);
    float res = q * sc;
    o[c] = (unsigned short)(__float_as_uint(res) >> 16);
  }
  ushort4 ov = {o[0], o[1], o[2], o[3]};
  ((ushort4*)out)[i] = ov;
}

// C[m][n] = sum_k A[m][k]*B[n][k] + bias[n];  A: M x K bf16, B: N x K bf16, C fp32.
// 256x256 tile, BK=64, 512 threads (8 waves as 2Mx4N, 128x64 per wave).
// 4 phases per K-tile (8-phase/2-tile template): per phase stage one 16KB
// half-tile of tile t+1 (2x global_load_lds dwordx4), ds_read 4-8 b128 frags,
// setprio(1) around 16 MFMA between raw s_barriers. Counted vmcnt(2) once per
// K-tile (never drains the pipeline). LDS XOR chunk-swizzle applied as
// inverse-swizzled GLOBAL source + swizzled ds_read offsets (dest stays linear
// as global_load_lds requires). XCD-chunked blockIdx swizzle for A-panel L2 reuse.
__global__ __launch_bounds__(512, 2) void gemm_bt(const unsigned short* __restrict__ A,
                                                  const unsigned short* __restrict__ B,
                                                  const float* __restrict__ bias,
                                                  float* __restrict__ C) {
  __shared__ unsigned short As[2][256 * 64];  // 64 KB (2 buffers x 32 KB)
  __shared__ unsigned short Bs[2][256 * 64];  // 64 KB
  const int t = threadIdx.x;
  // XCD-chunked bijective swizzle: 1024 blocks, 8 XCDs -> XCD k owns wg [128k,128k+128)
  const int wg = ((blockIdx.x & 7) << 7) | (blockIdx.x >> 3);
  const int m0 = (wg >> 2) << 8;  // 256 M-tiles
  const int n0 = (wg & 3) << 8;   // 4 N-tiles

  const int lane = t & 63, w = t >> 6;
  const int wm = (w >> 2) << 7;  // 0 or 128
  const int wn = (w & 3) << 6;   // 0,64,128,192
  const int quad = lane >> 4, r16 = lane & 15;

  // Staging: thread t covers linear LDS bytes [t*16, t*16+16) of an 8KB call
  // region; row rt = t>>3 (128 B rows), physical chunk t&7. Inverse swizzle on
  // the global source: logical chunk cl = (t&7) ^ (rt&7).
  const int rt = t >> 3;
  const int cl = (t & 7) ^ (rt & 7);
  const unsigned short* Ag = A + (size_t)(m0 + rt) * KK + cl * 8;
  const unsigned short* Bg = B + (size_t)(n0 + rt) * KK + cl * 8;
  char* AsW = (char*)As + t * 16;
  char* BsW = (char*)Bs + t * 16;
  // ds_read: row = (wm|wn) + mp*16 + r16, physical chunk = (kh*4+quad) ^ (r16&7)
  const char* AsR = (const char*)As + (wm + r16) * 128;
  const char* BsR = (const char*)Bs + (wn + r16) * 128;
  const int sw0 = (quad ^ (r16 & 7)) << 4;        // kh=0 swizzled chunk byte-offset
  const int sw1 = ((4 | quad) ^ (r16 & 7)) << 4;  // kh=1

#define STG_A(BUF, H, C_, T_)                                                     \
  gll16(Ag + (size_t)((H) * 128 + (C_) * 64) * KK + (size_t)(T_) * 64,            \
        AsW + (BUF) * 32768 + (H) * 16384 + (C_) * 8192)
#define STG_B(BUF, H, C_, T_)                                                     \
  gll16(Bg + (size_t)((H) * 128 + (C_) * 64) * KK + (size_t)(T_) * 64,            \
        BsW + (BUF) * 32768 + (H) * 16384 + (C_) * 8192)
#define LDA(BUF, MP, SW) (*(const bf16x8*)(AsR + (BUF) * 32768 + (MP) * 2048 + (SW)))
#define LDB(BUF, NP, SW) (*(const bf16x8*)(BsR + (BUF) * 32768 + (NP) * 2048 + (SW)))
#define MFMA16(MB)                                              \
  do {                                                          \
    acc[(MB) + 0][0] = mfma(a0, b0, acc[(MB) + 0][0]);          \
    acc[(MB) + 0][1] = mfma(a0, b1, acc[(MB) + 0][1]);          \
    acc[(MB) + 0][2] = mfma(a0, b2, acc[(MB) + 0][2]);          \
    acc[(MB) + 0][3] = mfma(a0, b3, acc[(MB) + 0][3]);          \
    acc[(MB) + 1][0] = mfma(a1, b0, acc[(MB) + 1][0]);          \
    acc[(MB) + 1][1] = mfma(a1, b1, acc[(MB) + 1][1]);          \
    acc[(MB) + 1][2] = mfma(a1, b2, acc[(MB) + 1][2]);          \
    acc[(MB) + 1][3] = mfma(a1, b3, acc[(MB) + 1][3]);          \
    acc[(MB) + 2][0] = mfma(a2, b0, acc[(MB) + 2][0]);          \
    acc[(MB) + 2][1] = mfma(a2, b1, acc[(MB) + 2][1]);          \
    acc[(MB) + 2][2] = mfma(a2, b2, acc[(MB) + 2][2]);          \
    acc[(MB) + 2][3] = mfma(a2, b3, acc[(MB) + 2][3]);          \
    acc[(MB) + 3][0] = mfma(a3, b0, acc[(MB) + 3][0]);          \
    acc[(MB) + 3][1] = mfma(a3, b1, acc[(MB) + 3][1]);          \
    acc[(MB) + 3][2] = mfma(a3, b2, acc[(MB) + 3][2]);          \
    acc[(MB) + 3][3] = mfma(a3, b3, acc[(MB) + 3][3]);          \
  } while (0)

  f32x4 acc[8][4] = {};

  // Prologue: stage K-tile 0 into buffer 0 (4 half-tiles = 8 loads, stay in flight)
  STG_A(0, 0, 0, 0); STG_A(0, 0, 1, 0);
  STG_A(0, 1, 0, 0); STG_A(0, 1, 1, 0);
  STG_B(0, 0, 0, 0); STG_B(0, 0, 1, 0);
  STG_B(0, 1, 0, 0); STG_B(0, 1, 1, 0);

#pragma unroll 2
  for (int kt = 0; kt < NT; ++kt) {
    const int bi = kt & 1;
    const int nx = bi ^ 1;
    const bool pf = (kt + 1) < NT;
    bf16x8 a0, a1, a2, a3, b0, b1, b2, b3;

    // ---- phase 0: stage A-half0(t+1); counted wait for tile t; mh0 x kh0
    if (pf) {
      STG_A(nx, 0, 0, kt + 1); STG_A(nx, 0, 1, kt + 1);
      asm volatile("s_waitcnt vmcnt(2)" ::: "memory");  // tile t landed, 2 in flight
    } else {
      asm volatile("s_waitcnt vmcnt(0)" ::: "memory");
    }
    __builtin_amdgcn_s_barrier();
    asm volatile("" ::: "memory");  // no LDS reads above this point
    a0 = LDA(bi, 0, sw0); a1 = LDA(bi, 1, sw0); a2 = LDA(bi, 2, sw0); a3 = LDA(bi, 3, sw0);
    b0 = LDB(bi, 0, sw0); b1 = LDB(bi, 1, sw0); b2 = LDB(bi, 2, sw0); b3 = LDB(bi, 3, sw0);
    __builtin_amdgcn_s_setprio(1);
    MFMA16(0);
    __builtin_amdgcn_s_setprio(0);
    __builtin_amdgcn_s_barrier();

    // ---- phase 1: read A[4..7] kh0; stage A-half1(t+1); mh1 x kh0 (B regs reused)
    a0 = LDA(bi, 4, sw0); a1 = LDA(bi, 5, sw0); a2 = LDA(bi, 6, sw0); a3 = LDA(bi, 7, sw0);
    if (pf) { STG_A(nx, 1, 0, kt + 1); STG_A(nx, 1, 1, kt + 1); }
    __builtin_amdgcn_s_barrier();
    __builtin_amdgcn_s_setprio(1);
    MFMA16(4);
    __builtin_amdgcn_s_setprio(0);
    __builtin_amdgcn_s_barrier();

    // ---- phase 2: read A[0..3]+B[0..3] kh1; stage B-half0(t+1); mh0 x kh1
    a0 = LDA(bi, 0, sw1); a1 = LDA(bi, 1, sw1); a2 = LDA(bi, 2, sw1); a3 = LDA(bi, 3, sw1);
    b0 = LDB(bi, 0, sw1); b1 = LDB(bi, 1, sw1); b2 = LDB(bi, 2, sw1); b3 = LDB(bi, 3, sw1);
    if (pf) { STG_B(nx, 0, 0, kt + 1); STG_B(nx, 0, 1, kt + 1); }
    __builtin_amdgcn_s_barrier();
    __builtin_amdgcn_s_setprio(1);
    MFMA16(0);
    __builtin_amdgcn_s_setprio(0);
    __builtin_amdgcn_s_barrier();

    // ---- phase 3: read A[4..7] kh1; stage B-half1(t+1); mh1 x kh1
    a0 = LDA(bi, 4, sw1); a1 = LDA(bi, 5, sw1); a2 = LDA(bi, 6, sw1); a3 = LDA(bi, 7, sw1);
    if (pf) { STG_B(nx, 1, 0, kt + 1); STG_B(nx, 1, 1, kt + 1); }
    __builtin_amdgcn_s_barrier();
    __builtin_amdgcn_s_setprio(1);
    MFMA16(4);
    __builtin_amdgcn_s_setprio(0);
    __builtin_amdgcn_s_barrier();
  }

  // Epilogue: C/D layout col = lane&15, row = quad*4 + reg (same as verified kernel)
  float bcol[4];
#pragma unroll
  for (int j = 0; j < 4; ++j) bcol[j] = bias[n0 + wn + j * 16 + r16];
#pragma unroll
  for (int mp = 0; mp < 8; ++mp) {
    const int rbase = m0 + wm + mp * 16 + quad * 4;
#pragma unroll
    for (int j = 0; j < 4; ++j) {
      const int col = n0 + wn + j * 16 + r16;
      float* Cp = C + (size_t)rbase * NN + col;
#pragma unroll
      for (int reg = 0; reg < 4; ++reg)
        Cp[(size_t)reg * NN] = acc[mp][j][reg] + bcol[j];
    }
  }
#undef STG_A
#undef STG_B
#undef LDA
#undef LDB
#undef MFMA16
}

extern "C" void kernel_launch(void* const* d_in, const int* in_sizes, int n_in,
                              void* d_out, int out_size, void* d_ws, size_t ws_size,
                              hipStream_t stream) {
  const float* x = (const float*)d_in[0];      // 8*8192*1024
  const float* wgt = (const float*)d_in[1];    // 1024*1024
  const float* bias = (const float*)d_in[2];   // 1024
  float* out = (float*)d_out;

  unsigned short* xq = (unsigned short*)d_ws;                  // 128 MB
  unsigned short* wq = xq + (size_t)MM * KK;                   // +2 MB

  mxfp_quant<<<(MM * (size_t)KK) / 1024, 256, 0, stream>>>(x, xq);    // 65536 blocks
  mxfp_quant<<<(NN * (size_t)KK) / 1024, 256, 0, stream>>>(wgt, wq);  // 1024 blocks
  gemm_bt<<<(MM / 256) * (NN / 256), 512, 0, stream>>>(xq, wq, bias, out);
}

// Round 2
// 579.970 us; speedup vs baseline: 1.0586x; 1.0243x over previous
//
#include <hip/hip_runtime.h>
#include <cstdint>
#include <cstddef>

#define MM 65536
#define NN 1024
#define KK 1024
#define NT 16  // KK / 64 K-tiles

typedef __bf16 bf16x8 __attribute__((ext_vector_type(8)));
typedef float f32x4 __attribute__((ext_vector_type(4)));

typedef const __attribute__((address_space(1))) unsigned int* gas_t;
typedef __attribute__((address_space(3))) unsigned int* las_t;

__device__ __forceinline__ void gll16(const void* g, void* l) {
  __builtin_amdgcn_global_load_lds((gas_t)g, (las_t)l, 16, 0, 0);
}

// exp2 for integer e in [-126, 127]
__device__ __forceinline__ float exp2i(int e) {
  return __int_as_float((e + 127) << 23);
}

__device__ __forceinline__ f32x4 mfma(bf16x8 a, bf16x8 b, f32x4 c) {
  return __builtin_amdgcn_mfma_f32_16x16x32_bf16(a, b, c, 0, 0, 0);
}

// MXFP fake-quant (block=32 along last dim), fp32 -> exact bf16.
// One float4 per lane; 8 consecutive lanes = one 32-elem block. (unchanged)
__global__ __launch_bounds__(256) void mxfp_quant(const float* __restrict__ in,
                                                  unsigned short* __restrict__ out) {
  size_t i = (size_t)blockIdx.x * 256 + threadIdx.x;
  float4 v = ((const float4*)in)[i];
  float a = fmaxf(fmaxf(fabsf(v.x), fabsf(v.y)), fmaxf(fabsf(v.z), fabsf(v.w)));
  a = fmaxf(a, __shfl_xor(a, 1));
  a = fmaxf(a, __shfl_xor(a, 2));
  a = fmaxf(a, __shfl_xor(a, 4));
  int ebits = (int)((__float_as_uint(a) >> 23) & 0xff);
  int se = (ebits > 0 ? ebits : 1) - 127 - 8;
  se = se < -126 ? -126 : se;
  float sinv = exp2i(-se);
  float sc = exp2i(se);

  float e[4] = {v.x, v.y, v.z, v.w};
  unsigned short o[4];
#pragma unroll
  for (int c = 0; c < 4; ++c) {
    float vv = e[c] * sinv;
    int pe = (int)((__float_as_uint(vv) >> 23) & 0xff) - 127;
    pe = pe < -6 ? -6 : pe;
    float r = floorf(fabsf(vv) * exp2i(6 - pe) + 0.5f);
    float q = copysignf(r * exp2i(pe - 6), vv);
    q = fminf(fmaxf(q, -448.f), 448.f);
    float res = q * sc;
    o[c] = (unsigned short)(__float_as_uint(res) >> 16);
  }
  ushort4 ov = {o[0], o[1], o[2], o[3]};
  ((ushort4*)out)[i] = ov;
}

// C[m][n] = sum_k A[m][k]*B[n][k] + bias[n];  A: M x K bf16, B: N x K bf16, C fp32.
// 256x256 tile, BK=64, 512 threads (8 waves as 2Mx4N, 128x64 per wave).
//
// K-half staged pipeline (m201-faithful): the staged unit is a K-HALF of one
// operand ([256 rows][32 k] = 16 KB = 2 gll calls), so each phase's MFMA
// consumes exactly one (operand, kh) unit uniformly across waves. Stage order
// per tile t (staging t+1): ph0->A-k0, ph1->B-k0, ph2->A-k1, ph3->B-k1.
// Counted vmcnt(6) at ph0 and ph2 keeps 3 half-tiles (6 loads) in flight;
// issue->wait distance is 3-4 phases (~3000 cyc >> ~900 cyc HBM latency).
// LDS [buf][kh][256r][32k], 64 B rows; ds_read_b128 chunk swizzle
// phys = quad ^ ((r16>>1)&3) is exactly balanced (8 lanes / 16 B slot);
// inverse swizzle applied on the global source (LDS dest stays linear, as
// global_load_lds requires). XCD-chunked blockIdx swizzle for A-panel L2 reuse.
__global__ __launch_bounds__(512, 2) void gemm_bt(const unsigned short* __restrict__ A,
                                                  const unsigned short* __restrict__ B,
                                                  const float* __restrict__ bias,
                                                  float* __restrict__ C) {
  __shared__ unsigned short As[2][2][128 * 64];  // [buf][kh][256r x 32k] = 64 KB
  __shared__ unsigned short Bs[2][2][128 * 64];  // 64 KB
  const int t = threadIdx.x;
  // XCD-chunked bijective swizzle: 1024 blocks, 8 XCDs -> XCD k owns wg [128k,128k+128)
  const int wg = ((blockIdx.x & 7) << 7) | (blockIdx.x >> 3);
  const int m0 = (wg >> 2) << 8;  // 256 M-tiles
  const int n0 = (wg & 3) << 8;   // 4 N-tiles

  const int lane = t & 63, w = t >> 6;
  const int wm = (w >> 2) << 7;  // 0 or 128
  const int wn = (w & 3) << 6;   // 0,64,128,192
  const int quad = lane >> 4, r16 = lane & 15;

  // Staging: one gll call = 8 KB = 128 rows x 64 B. Thread t covers row
  // rt = t>>2, physical 16 B chunk pc = t&3. Inverse swizzle on the global
  // source: logical chunk lc = pc ^ ((rt>>1)&3).
  const int rt = t >> 2;
  const int lc = (t & 3) ^ ((rt >> 1) & 3);
  const unsigned short* Ag = A + (size_t)(m0 + rt) * KK + lc * 8;
  const unsigned short* Bg = B + (size_t)(n0 + rt) * KK + lc * 8;
  char* AsW = (char*)As + t * 16;
  char* BsW = (char*)Bs + t * 16;
  // ds_read: row r = (wm|wn) + idx*16 + r16, k-chunk quad within the K-half.
  // Physical chunk = quad ^ ((r16>>1)&3)  (bits 1-2 of r == bits 1-2 of r16).
  const int swq = (quad ^ ((r16 >> 1) & 3)) << 4;
  const char* AsR = (const char*)As + (wm + r16) * 64 + swq;
  const char* BsR = (const char*)Bs + (wn + r16) * 64 + swq;

// Stage one K-half of one operand for tile T_ into buffer BUF:
// region (KH, row-half H): rows H*128+rt, k = T_*64 + KH*32 + lc*8.
#define STG_A(BUF, KH, H, T_)                                              \
  gll16(Ag + (size_t)(H) * 128 * KK + (size_t)(T_) * 64 + (KH) * 32,       \
        AsW + (BUF) * 32768 + (KH) * 16384 + (H) * 8192)
#define STG_B(BUF, KH, H, T_)                                              \
  gll16(Bg + (size_t)(H) * 128 * KK + (size_t)(T_) * 64 + (KH) * 32,       \
        BsW + (BUF) * 32768 + (KH) * 16384 + (H) * 8192)
#define LDA(BUF, KH, MP) \
  (*(const bf16x8*)(AsR + (BUF) * 32768 + (KH) * 16384 + (MP) * 1024))
#define LDB(BUF, KH, NP) \
  (*(const bf16x8*)(BsR + (BUF) * 32768 + (KH) * 16384 + (NP) * 1024))
#define MFMA16(MB)                                              \
  do {                                                          \
    acc[(MB) + 0][0] = mfma(a0, b0, acc[(MB) + 0][0]);          \
    acc[(MB) + 0][1] = mfma(a0, b1, acc[(MB) + 0][1]);          \
    acc[(MB) + 0][2] = mfma(a0, b2, acc[(MB) + 0][2]);          \
    acc[(MB) + 0][3] = mfma(a0, b3, acc[(MB) + 0][3]);          \
    acc[(MB) + 1][0] = mfma(a1, b0, acc[(MB) + 1][0]);          \
    acc[(MB) + 1][1] = mfma(a1, b1, acc[(MB) + 1][1]);          \
    acc[(MB) + 1][2] = mfma(a1, b2, acc[(MB) + 1][2]);          \
    acc[(MB) + 1][3] = mfma(a1, b3, acc[(MB) + 1][3]);          \
    acc[(MB) + 2][0] = mfma(a2, b0, acc[(MB) + 2][0]);          \
    acc[(MB) + 2][1] = mfma(a2, b1, acc[(MB) + 2][1]);          \
    acc[(MB) + 2][2] = mfma(a2, b2, acc[(MB) + 2][2]);          \
    acc[(MB) + 2][3] = mfma(a2, b3, acc[(MB) + 2][3]);          \
    acc[(MB) + 3][0] = mfma(a3, b0, acc[(MB) + 3][0]);          \
    acc[(MB) + 3][1] = mfma(a3, b1, acc[(MB) + 3][1]);          \
    acc[(MB) + 3][2] = mfma(a3, b2, acc[(MB) + 3][2]);          \
    acc[(MB) + 3][3] = mfma(a3, b3, acc[(MB) + 3][3]);          \
  } while (0)

  f32x4 acc[8][4] = {};

  // Prologue: stage tile 0 into buffer 0 in consumption order (8 calls in flight).
  STG_A(0, 0, 0, 0); STG_A(0, 0, 1, 0);
  STG_B(0, 0, 0, 0); STG_B(0, 0, 1, 0);
  STG_A(0, 1, 0, 0); STG_A(0, 1, 1, 0);
  STG_B(0, 1, 0, 0); STG_B(0, 1, 1, 0);

#pragma unroll 2
  for (int kt = 0; kt < NT; ++kt) {
    const int bi = kt & 1;
    const int nx = bi ^ 1;
    const bool pf = (kt + 1) < NT;
    bf16x8 a0, a1, a2, a3, b0, b1, b2, b3;

    // ---- phase 0: stage A-k0(t+1); wait for A-k0(t)+B-k0(t); mh0 x kh0
    if (pf) {
      STG_A(nx, 0, 0, kt + 1); STG_A(nx, 0, 1, kt + 1);
      asm volatile("s_waitcnt vmcnt(6)" ::: "memory");  // 3 half-tiles in flight
    } else {
      asm volatile("s_waitcnt vmcnt(4)" ::: "memory");  // tail: k0 halves landed
    }
    __builtin_amdgcn_s_barrier();
    asm volatile("" ::: "memory");
    a0 = LDA(bi, 0, 0); a1 = LDA(bi, 0, 1); a2 = LDA(bi, 0, 2); a3 = LDA(bi, 0, 3);
    b0 = LDB(bi, 0, 0); b1 = LDB(bi, 0, 1); b2 = LDB(bi, 0, 2); b3 = LDB(bi, 0, 3);
    __builtin_amdgcn_s_setprio(1);
    MFMA16(0);
    __builtin_amdgcn_s_setprio(0);
    __builtin_amdgcn_s_barrier();

    // ---- phase 1: read A[4..7] kh0; stage B-k0(t+1); mh1 x kh0 (B regs reused)
    a0 = LDA(bi, 0, 4); a1 = LDA(bi, 0, 5); a2 = LDA(bi, 0, 6); a3 = LDA(bi, 0, 7);
    if (pf) { STG_B(nx, 0, 0, kt + 1); STG_B(nx, 0, 1, kt + 1); }
    __builtin_amdgcn_s_barrier();
    __builtin_amdgcn_s_setprio(1);
    MFMA16(4);
    __builtin_amdgcn_s_setprio(0);
    __builtin_amdgcn_s_barrier();

    // ---- phase 2: stage A-k1(t+1); wait for A-k1(t)+B-k1(t); mh0 x kh1
    if (pf) {
      STG_A(nx, 1, 0, kt + 1); STG_A(nx, 1, 1, kt + 1);
      asm volatile("s_waitcnt vmcnt(6)" ::: "memory");
    } else {
      asm volatile("s_waitcnt vmcnt(0)" ::: "memory");  // tail: everything landed
    }
    __builtin_amdgcn_s_barrier();
    asm volatile("" ::: "memory");
    a0 = LDA(bi, 1, 0); a1 = LDA(bi, 1, 1); a2 = LDA(bi, 1, 2); a3 = LDA(bi, 1, 3);
    b0 = LDB(bi, 1, 0); b1 = LDB(bi, 1, 1); b2 = LDB(bi, 1, 2); b3 = LDB(bi, 1, 3);
    __builtin_amdgcn_s_setprio(1);
    MFMA16(0);
    __builtin_amdgcn_s_setprio(0);
    __builtin_amdgcn_s_barrier();

    // ---- phase 3: read A[4..7] kh1; stage B-k1(t+1); mh1 x kh1
    a0 = LDA(bi, 1, 4); a1 = LDA(bi, 1, 5); a2 = LDA(bi, 1, 6); a3 = LDA(bi, 1, 7);
    if (pf) { STG_B(nx, 1, 0, kt + 1); STG_B(nx, 1, 1, kt + 1); }
    __builtin_amdgcn_s_barrier();
    __builtin_amdgcn_s_setprio(1);
    MFMA16(4);
    __builtin_amdgcn_s_setprio(0);
    __builtin_amdgcn_s_barrier();
  }

  // Epilogue: C/D layout col = lane&15, row = quad*4 + reg
  float bcol[4];
#pragma unroll
  for (int j = 0; j < 4; ++j) bcol[j] = bias[n0 + wn + j * 16 + r16];
#pragma unroll
  for (int mp = 0; mp < 8; ++mp) {
    const int rbase = m0 + wm + mp * 16 + quad * 4;
#pragma unroll
    for (int j = 0; j < 4; ++j) {
      const int col = n0 + wn + j * 16 + r16;
      float* Cp = C + (size_t)rbase * NN + col;
#pragma unroll
      for (int reg = 0; reg < 4; ++reg)
        Cp[(size_t)reg * NN] = acc[mp][j][reg] + bcol[j];
    }
  }
#undef STG_A
#undef STG_B
#undef LDA
#undef LDB
#undef MFMA16
}

extern "C" void kernel_launch(void* const* d_in, const int* in_sizes, int n_in,
                              void* d_out, int out_size, void* d_ws, size_t ws_size,
                              hipStream_t stream) {
  const float* x = (const float*)d_in[0];      // 8*8192*1024
  const float* wgt = (const float*)d_in[1];    // 1024*1024
  const float* bias = (const float*)d_in[2];   // 1024
  float* out = (float*)d_out;

  unsigned short* xq = (unsigned short*)d_ws;                  // 128 MB
  unsigned short* wq = xq + (size_t)MM * KK;                   // +2 MB

  mxfp_quant<<<(MM * (size_t)KK) / 1024, 256, 0, stream>>>(x, xq);    // 65536 blocks
  mxfp_quant<<<(NN * (size_t)KK) / 1024, 256, 0, stream>>>(wgt, wq);  // 1024 blocks
  gemm_bt<<<(MM / 256) * (NN / 256), 512, 0, stream>>>(xq, wq, bias, out);
}